// Round 11
// baseline (105.026 us; speedup 1.0000x reference)
//
#include <hip/hip_runtime.h>

typedef __attribute__((ext_vector_type(4))) float f32x4;
typedef __attribute__((ext_vector_type(2))) float f32x2;
typedef __attribute__((ext_vector_type(8))) short bf16x8;

#define NEDGE 100000
#define NNODE 10000
#define INV40f 0.15811388300841897f
#define INV120f 0.09128709291752769f

__device__ inline short f2bf(float f) {
    unsigned u = __builtin_bit_cast(unsigned, f);
    u = (u + 0x7fffu + ((u >> 16) & 1u)) >> 16;
    return (short)u;
}

__device__ __forceinline__ float bperm(int byteIdx, float v) {
    return __builtin_bit_cast(float,
        __builtin_amdgcn_ds_bpermute(byteIdx, __builtin_bit_cast(int, v)));
}

__device__ __forceinline__ void stage16(const void* gsrc, void* ldst) {
    __builtin_amdgcn_global_load_lds(
        (const __attribute__((address_space(1))) unsigned*)gsrc,
        (__attribute__((address_space(3))) unsigned*)(unsigned long long)(uintptr_t)ldst,
        16, 0, 0);
}

#define MFMA16(A,B,C) __builtin_amdgcn_mfma_f32_16x16x32_bf16((A),(B),(C),0,0,0)

// prep: fc2_w -> fc2_wt [c][k] bf16 via LDS transpose; fc1_w -> fc1_wt; b>=26: hist build (CSR mode)
__global__ __launch_bounds__(256) void prep(const float* __restrict__ fc1_w,
                                            const float* __restrict__ fc2_w,
                                            const int* __restrict__ edge_index,
                                            short* __restrict__ fc1_wt,
                                            short* __restrict__ fc2_wt,
                                            int* __restrict__ hist) {
    const int b = blockIdx.x, t = threadIdx.x;
    if (b < 25) {
        __shared__ short tile[64 * 66];
        const int c0 = b * 64;
        #pragma unroll
        for (int rep = 0; rep < 16; rep++) {
            const int idx = rep * 256 + t;
            const int k = idx >> 6, c = idx & 63;
            tile[k * 66 + c] = f2bf(fc2_w[(size_t)k * 1600 + c0 + c]);
        }
        __syncthreads();
        #pragma unroll
        for (int rep = 0; rep < 16; rep++) {
            const int idx = rep * 256 + t;
            const int c = idx >> 6, k = idx & 63;
            fc2_wt[(size_t)(c0 + c) * 64 + k] = tile[k * 66 + c];
        }
    } else if (b == 25) {
        #pragma unroll
        for (int rep = 0; rep < 16; rep++) {
            const int i = rep * 256 + t;
            fc1_wt[(i & 63) * 64 + (i >> 6)] = f2bf(fc1_w[i]);
        }
    } else {
        const int e = (b - 26) * 256 + t;
        if (e < NEDGE) atomicAdd(&hist[edge_index[e]], 1);
    }
}

// 8 waves/block, 16 edges/wave. LDS 41.2KB (h_s aliased into cbB) -> 3 blocks/CU.
// CSR=true: write padded 64-f32 row at cursor-assigned slot. CSR=false: edge-ordered 56-f32 row + hist build.
template<bool CSR>
__global__ __launch_bounds__(512, 4) void edge_fused(
    const float* __restrict__ node_attr,
    const float* __restrict__ edge_attr,
    const float* __restrict__ edge_sh,
    const int*   __restrict__ edge_index,
    const float* __restrict__ fc1_b,
    const float* __restrict__ fc2_b,
    const short* __restrict__ fc1_wt,
    const short* __restrict__ fc2_wt,
    float* __restrict__ tp_out,
    int*   __restrict__ histcur)
{
    // LDS: cbA 16384 @0 | cbB 16384 @16384 | shb 8x256 @32768 | bias 6400 @34816 = 41216
    // h_s (8x2KB) ALIASED into cbB: h written+read entirely before barrier0; cbB first DMA'd at phase 1.
    __shared__ __align__(16) char lds[41216];
    char* cbA = lds;
    char* cbB = lds + 16384;
    float* bias_s = (float*)(lds + 34816);

    const int tid  = threadIdx.x;
    const int wid  = tid >> 6;
    const int wtid = tid & 63;
    const int l15  = wtid & 15;
    const int lg   = wtid >> 4;
    const int lg4  = lg * 4;
    const int e0   = blockIdx.x * 128 + wid * 16;
    const bool active = (e0 < NEDGE);

    char*  h_s = cbB + wid * 2048;
    float* shb = (float*)(lds + 32768 + wid * 256);

#define STAGE1(CH, BUF, J) do { \
        const int _o = (wid * 2 + (J)) * 1024 + wtid * 16; \
        const int _g = _o ^ (((_o >> 7) & 7) << 4); \
        stage16((const char*)fc2_wt + (CH) * 16384 + _g, (BUF) + (wid * 2 + (J)) * 1024); \
    } while (0)
#define STAGE_FULL(CH, BUF) do { STAGE1(CH, BUF, 0); STAGE1(CH, BUF, 1); } while (0)

    STAGE_FULL(0, cbA);   // chunk 0 in flight; overlaps whole prologue (cbA untouched by prologue)

    // ---- bias -> LDS ----
    if (tid < 400) {
        *(f32x4*)(bias_s + tid * 4) = *(const f32x4*)(fc2_b + tid * 4);
    }

    // ---- edge meta ----
    int dst_r = 0, slot_r = 0;
    if (active && wtid < 16) {
        dst_r = edge_index[NEDGE + e0 + wtid];
        const int src = edge_index[e0 + wtid];
        const f32x4 sh_r = *(const f32x4*)(edge_sh + (size_t)(e0 + wtid) * 4);
        slot_r = atomicAdd(&histcur[src], 1);   // CSR: slot; fallback: hist build
        *(f32x4*)(shb + wtid * 4) = sh_r;
    }
    const int p_e = __shfl(slot_r, l15, 64);

    bf16x8 ha0, ha1;
    f32x4 shv = {0.f, 0.f, 0.f, 0.f};
    float c00r[8], cb1r[8], c10r[6], c11r[2];
    int vidx[4];
    #pragma unroll
    for (int g = 0; g < 4; g++) vidx[g] = (g * 16 + l15) * 4;

    if (active) {
        // ---- fc1 A loads ----
        const float* pa = edge_attr + (size_t)(e0 + l15) * 64 + lg * 8;
        const f32x4 va0 = *(const f32x4*)(pa);
        const f32x4 va1 = *(const f32x4*)(pa + 4);
        const f32x4 va2 = *(const f32x4*)(pa + 32);
        const f32x4 va3 = *(const f32x4*)(pa + 36);

        // ---- per-lane table slices ----
        const int dstm = __shfl(dst_r, l15, 64);
        const float* nap = node_attr + (size_t)dstm * 56;
        const f32x4 x0a = *(const f32x4*)(nap + lg * 8);
        const f32x4 x0b = *(const f32x4*)(nap + lg * 8 + 4);
        const f32x2 x1a = *(const f32x2*)(nap + 32 + lg * 6);
        const f32x2 x1b = *(const f32x2*)(nap + 34 + lg * 6);
        const f32x2 x1c = *(const f32x2*)(nap + 36 + lg * 6);
        shv = *(const f32x4*)(shb + l15 * 4);   // same-wave LDS RAW, in-order

        const float s0 = shv[0];
        #pragma unroll
        for (int j = 0; j < 4; j++) {
            cb1r[j]     = INV40f * x0a[j];
            cb1r[4 + j] = INV40f * x0b[j];
            c00r[j]     = s0 * cb1r[j];
            c00r[4 + j] = s0 * cb1r[4 + j];
        }
        const float i40s0 = INV40f * s0;
        c10r[0] = i40s0 * x1a[0]; c10r[1] = i40s0 * x1a[1]; c10r[2] = i40s0 * x1b[0];
        c10r[3] = i40s0 * x1b[1]; c10r[4] = i40s0 * x1c[0]; c10r[5] = i40s0 * x1c[1];
        c11r[0] = INV120f * (x1a[0]*shv[1] + x1a[1]*shv[2] + x1b[0]*shv[3]);
        c11r[1] = INV120f * (x1b[1]*shv[1] + x1c[0]*shv[2] + x1c[1]*shv[3]);

        // ---- fc1 -> h (relu, bf16) via swizzled wave-private LDS transpose (in cbB region) ----
        bf16x8 a0, a1;
        #pragma unroll
        for (int i = 0; i < 4; i++) {
            a0[i] = f2bf(va0[i]); a0[4+i] = f2bf(va1[i]);
            a1[i] = f2bf(va2[i]); a1[4+i] = f2bf(va3[i]);
        }
        #pragma unroll
        for (int nf0 = 0; nf0 < 4; nf0++) {
            const bf16x8 b0 = *(const bf16x8*)(fc1_wt + (nf0*16 + l15)*64 + lg*8);
            const bf16x8 b1 = *(const bf16x8*)(fc1_wt + (nf0*16 + l15)*64 + 32 + lg*8);
            const float bias = fc1_b[nf0*16 + l15];
            f32x4 c = {bias, bias, bias, bias};
            c = MFMA16(a0, b0, c);
            c = MFMA16(a1, b1, c);
            #pragma unroll
            for (int reg = 0; reg < 4; reg++) {
                const int row = lg4 + reg;
                *(short*)(h_s + ((row*128 + (nf0*16 + l15)*2) ^ ((row & 7) << 4))) =
                    f2bf(fmaxf(c[reg], 0.0f));
            }
        }
        ha0 = *(const bf16x8*)(h_s + ((l15*128 +      lg*16) ^ ((l15 & 7) << 4)));
        ha1 = *(const bf16x8*)(h_s + ((l15*128 + 64 + lg*16) ^ ((l15 & 7) << 4)));
    }

    // ---- fc2 consume state ----
    const int hswz = (l15 & 7) << 4;
    const int ro0 = (l15 * 128 + lg * 16) ^ hswz;
    const int ro1 = (l15 * 128 + lg * 16 + 64) ^ hswz;
    const int usel = lg >> 1;
    float acc0[2][4] = {{0,0,0,0},{0,0,0,0}};
    float ab1[4] = {0,0,0,0};
    float b2v[12] = {};

    auto cons_w00 = [&](const char* cb, int ch) {
        bf16x8 pb0[3], pb1[3]; f32x4 pc[3];
        #pragma unroll
        for (int k = 0; k < 3; k++) {
            pb0[k] = *(const bf16x8*)(cb + k * 2048 + ro0);
            pb1[k] = *(const bf16x8*)(cb + k * 2048 + ro1);
            pc[k]  = *(const f32x4*)(bias_s + (ch * 8 + k) * 16 + lg4);
        }
        #pragma unroll
        for (int i = 0; i < 8; i++) {
            const int s = i % 3;
            const bf16x8 b0 = pb0[s], b1 = pb1[s];
            f32x4 c = pc[s];
            if (i + 3 < 8) {
                pb0[s] = *(const bf16x8*)(cb + (i + 3) * 2048 + ro0);
                pb1[s] = *(const bf16x8*)(cb + (i + 3) * 2048 + ro1);
                pc[s]  = *(const f32x4*)(bias_s + (ch * 8 + i + 3) * 16 + lg4);
            }
            c = MFMA16(b0, ha0, c);
            c = MFMA16(b1, ha1, c);
            const int nf = ch * 8 + i;
            const int u = nf >> 1, hi = nf & 1;
            const float cv = bperm(vidx[u >> 3], c00r[u & 7]);
            #pragma unroll
            for (int reg = 0; reg < 4; reg++) acc0[hi][reg] += cv * c[reg];
        }
    };
    auto cons_w01 = [&](const char* cb, int rbase) {
        bf16x8 pb0[3], pb1[3]; f32x4 pc[3];
        #pragma unroll
        for (int k = 0; k < 3; k++) {
            pb0[k] = *(const bf16x8*)(cb + k * 2048 + ro0);
            pb1[k] = *(const bf16x8*)(cb + k * 2048 + ro1);
            pc[k]  = *(const f32x4*)(bias_s + (64 + rbase + k) * 16 + lg4);
        }
        #pragma unroll
        for (int i = 0; i < 8; i++) {
            const int s = i % 3;
            const bf16x8 b0 = pb0[s], b1 = pb1[s];
            f32x4 c = pc[s];
            if (i + 3 < 8) {
                pb0[s] = *(const bf16x8*)(cb + (i + 3) * 2048 + ro0);
                pb1[s] = *(const bf16x8*)(cb + (i + 3) * 2048 + ro1);
                pc[s]  = *(const f32x4*)(bias_s + (64 + rbase + i + 3) * 16 + lg4);
            }
            c = MFMA16(b0, ha0, c);
            c = MFMA16(b1, ha1, c);
            const int nfl_r = rbase + i;
            const int r0 = (2 * nfl_r) & 7, g = nfl_r >> 2;
            const float e0v = bperm(vidx[g], cb1r[r0]);
            const float e1v = bperm(vidx[g], cb1r[r0 + 1]);
            const float cv = usel ? e1v : e0v;
            #pragma unroll
            for (int reg = 0; reg < 4; reg++) ab1[reg] += cv * c[reg];
        }
    };
    auto cons_w10 = [&](const char* cb, int fb) {
        bf16x8 pb0[2], pb1[2]; f32x4 pc[2];
        #pragma unroll
        for (int k = 0; k < 2; k++) {
            pb0[k] = *(const bf16x8*)(cb + (fb + k) * 2048 + ro0);
            pb1[k] = *(const bf16x8*)(cb + (fb + k) * 2048 + ro1);
            pc[k]  = *(const f32x4*)(bias_s + (80 + k) * 16 + lg4);
        }
        #pragma unroll
        for (int i = 0; i < 4; i++) {
            const int s = i % 2;
            const bf16x8 b0 = pb0[s], b1 = pb1[s];
            f32x4 c = pc[s];
            if (i + 2 < 4) {
                pb0[s] = *(const bf16x8*)(cb + (fb + i + 2) * 2048 + ro0);
                pb1[s] = *(const bf16x8*)(cb + (fb + i + 2) * 2048 + ro1);
                pc[s]  = *(const f32x4*)(bias_s + (80 + i + 2) * 16 + lg4);
            }
            c = MFMA16(b0, ha0, c);
            c = MFMA16(b1, ha1, c);
            #pragma unroll
            for (int k = 0; k < 3; k++) {
                const float e0v = bperm(vidx[i], c10r[k]);
                const float e1v = bperm(vidx[i], c10r[3 + k]);
                const float cv = usel ? e1v : e0v;
                #pragma unroll
                for (int reg = 0; reg < 4; reg++) b2v[reg * 3 + k] += cv * c[reg];
            }
        }
    };
    auto cons_w11_4 = [&](const char* cb, int fb, int ridx0) {
        bf16x8 pb0[2], pb1[2]; f32x4 pc[2];
        #pragma unroll
        for (int k = 0; k < 2; k++) {
            pb0[k] = *(const bf16x8*)(cb + (fb + k) * 2048 + ro0);
            pb1[k] = *(const bf16x8*)(cb + (fb + k) * 2048 + ro1);
            pc[k]  = *(const f32x4*)(bias_s + (84 + ridx0 + k) * 16 + lg4);
        }
        #pragma unroll
        for (int i = 0; i < 4; i++) {
            const int s = i % 2;
            const bf16x8 b0 = pb0[s], b1 = pb1[s];
            f32x4 c = pc[s];
            if (i + 2 < 4) {
                pb0[s] = *(const bf16x8*)(cb + (fb + i + 2) * 2048 + ro0);
                pb1[s] = *(const bf16x8*)(cb + (fb + i + 2) * 2048 + ro1);
                pc[s]  = *(const f32x4*)(bias_s + (84 + ridx0 + i + 2) * 16 + lg4);
            }
            c = MFMA16(b0, ha0, c);
            c = MFMA16(b1, ha1, c);
            const int ridx = ridx0 + i;
            const int up = ridx >> 1, hi = ridx & 1;
            const float cv = bperm(vidx[up >> 1], c11r[up & 1]);
            #pragma unroll
            for (int reg = 0; reg < 4; reg++) acc0[hi][reg] += cv * c[reg];
        }
    };
    auto cons_w11_8 = [&](const char* cb, int ridx0) {
        bf16x8 pb0[3], pb1[3]; f32x4 pc[3];
        #pragma unroll
        for (int k = 0; k < 3; k++) {
            pb0[k] = *(const bf16x8*)(cb + k * 2048 + ro0);
            pb1[k] = *(const bf16x8*)(cb + k * 2048 + ro1);
            pc[k]  = *(const f32x4*)(bias_s + (84 + ridx0 + k) * 16 + lg4);
        }
        #pragma unroll
        for (int i = 0; i < 8; i++) {
            const int s = i % 3;
            const bf16x8 b0 = pb0[s], b1 = pb1[s];
            f32x4 c = pc[s];
            if (i + 3 < 8) {
                pb0[s] = *(const bf16x8*)(cb + (i + 3) * 2048 + ro0);
                pb1[s] = *(const bf16x8*)(cb + (i + 3) * 2048 + ro1);
                pc[s]  = *(const f32x4*)(bias_s + (84 + ridx0 + i + 3) * 16 + lg4);
            }
            c = MFMA16(b0, ha0, c);
            c = MFMA16(b1, ha1, c);
            const int ridx = ridx0 + i;
            const int up = ridx >> 1, hi = ridx & 1;
            const float cv = bperm(vidx[up >> 1], c11r[up & 1]);
            #pragma unroll
            for (int reg = 0; reg < 4; reg++) acc0[hi][reg] += cv * c[reg];
        }
    };

    // ---- 13-phase chunk pipeline ----
    __syncthreads();                                   // chunk 0 + bias ready; all h reads done
    STAGE_FULL(1,  cbB); if (active) cons_w00(cbA, 0); __syncthreads();
    STAGE_FULL(2,  cbA); if (active) cons_w00(cbB, 1); __syncthreads();
    STAGE_FULL(3,  cbB); if (active) cons_w00(cbA, 2); __syncthreads();
    STAGE_FULL(4,  cbA); if (active) cons_w00(cbB, 3); __syncthreads();
    STAGE_FULL(5,  cbB); if (active) cons_w00(cbA, 4); __syncthreads();
    STAGE_FULL(6,  cbA); if (active) cons_w00(cbB, 5); __syncthreads();
    STAGE_FULL(7,  cbB); if (active) cons_w00(cbA, 6); __syncthreads();
    STAGE_FULL(8,  cbA); if (active) cons_w00(cbB, 7); __syncthreads();
    STAGE_FULL(9,  cbB); if (active) cons_w01(cbA, 0); __syncthreads();
    STAGE_FULL(10, cbA); if (active) cons_w01(cbB, 8); __syncthreads();
    STAGE_FULL(11, cbB); if (active) { cons_w10(cbA, 0); cons_w11_4(cbA, 4, 0); } __syncthreads();
    STAGE_FULL(12, cbA); if (active) cons_w11_8(cbB, 4); __syncthreads();
                         if (active) cons_w11_4(cbA, 0, 12);

    if (!active) return;

    // ---- emit ----
    float* orow = CSR ? (tp_out + (size_t)p_e * 64)
                      : (tp_out + (size_t)(e0 + l15) * 56);
    {
        const f32x4 o0 = {acc0[0][0], acc0[0][1], acc0[0][2], acc0[0][3]};
        const f32x4 o1 = {acc0[1][0], acc0[1][1], acc0[1][2], acc0[1][3]};
        *(f32x4*)(orow + lg4)      = o0;
        *(f32x4*)(orow + 16 + lg4) = o1;
    }
    #pragma unroll
    for (int reg = 0; reg < 4; reg++) ab1[reg] += __shfl_xor(ab1[reg], 32, 64);
    #pragma unroll
    for (int m = 0; m < 12; m++) b2v[m] += __shfl_xor(b2v[m], 32, 64);
    if (lg < 2) {
        float ov[12];
        #pragma unroll
        for (int reg = 0; reg < 4; reg++) {
            ov[reg*3 + 0] = shv[1] * ab1[reg] + b2v[reg*3 + 0];
            ov[reg*3 + 1] = shv[2] * ab1[reg] + b2v[reg*3 + 1];
            ov[reg*3 + 2] = shv[3] * ab1[reg] + b2v[reg*3 + 2];
        }
        float* p1 = orow + 32 + lg * 12;
        *(f32x4*)(p1)     = f32x4{ov[0], ov[1], ov[2],  ov[3]};
        *(f32x4*)(p1 + 4) = f32x4{ov[4], ov[5], ov[6],  ov[7]};
        *(f32x4*)(p1 + 8) = f32x4{ov[8], ov[9], ov[10], ov[11]};
    } else if (CSR) {
        // fill padding bytes 224..255 so line 3 is fully written (no RMW fetch)
        *(f32x4*)(orow + 56 + (lg - 2) * 4) = f32x4{0.f, 0.f, 0.f, 0.f};
    }
#undef STAGE1
#undef STAGE_FULL
}

// exclusive prefix scan of hist[10000] -> offsets[10001], cursor (wave-shuffle scan)
__global__ __launch_bounds__(256) void scan_hist(const int* __restrict__ hist,
                                                 int* __restrict__ offsets,
                                                 int* __restrict__ cursor) {
    __shared__ int wsum[4];
    const int t = threadIdx.x;
    const int lane = t & 63;
    const int w = t >> 6;
    const int n0 = t * 40;
    int s = 0;
    if (n0 < NNODE) {
        for (int j = 0; j < 40; j++) s += hist[n0 + j];
    }
    int incl = s;
    #pragma unroll
    for (int d = 1; d < 64; d <<= 1) {
        const int v = __shfl_up(incl, d, 64);
        if (lane >= d) incl += v;
    }
    if (lane == 63) wsum[w] = incl;
    __syncthreads();
    int base = 0;
    for (int ww = 0; ww < 4; ww++) base += (ww < w) ? wsum[ww] : 0;
    if (n0 < NNODE) {
        int run = base + incl - s;
        for (int j = 0; j < 40; j++) {
            const int h = hist[n0 + j];
            offsets[n0 + j] = run; cursor[n0 + j] = run; run += h;
        }
    }
    if (t == 0) offsets[NNODE] = NEDGE;
}

__global__ __launch_bounds__(256) void fill_perm(const int* __restrict__ edge_index,
                                                 int* __restrict__ cursor,
                                                 int* __restrict__ perm) {
    const int e = blockIdx.x * 256 + threadIdx.x;
    if (e < NEDGE) {
        const int s = edge_index[e];
        const int p = atomicAdd(&cursor[s], 1);
        perm[p] = e;
    }
}

// segment mean + residual + BN partial stats. PERM=true: 56-f32 rows via perm; false: contiguous 64-f32 rows.
template<bool PERM>
__global__ __launch_bounds__(256) void node_agg(
    const float* __restrict__ tp_out, const int* __restrict__ offsets,
    const int* __restrict__ perm,
    const float* __restrict__ node_attr, float* __restrict__ out,
    float* __restrict__ stats)
{
    __shared__ float part[72];
    const int tid = threadIdx.x;
    if (tid < 72) part[tid] = 0.0f;
    __syncthreads();
    const int n = blockIdx.x * 16 + (tid >> 4);
    const int q = tid & 15;
    if (n < NNODE && q < 14) {
        const int st = offsets[n], en = offsets[n + 1];
        f32x4 acc = {0.f, 0.f, 0.f, 0.f};
        for (int r = st; r < en; r++) {
            const size_t row = PERM ? (size_t)perm[r] * 56 : (size_t)r * 64;
            acc += *(const f32x4*)(tp_out + row + q * 4);
        }
        const float inv = 1.0f / fmaxf((float)(en - st), 1.0f);
        const int c0 = q * 4;
        const f32x4 res = *(const f32x4*)(node_attr + (size_t)n * 56 + c0);
        f32x4 val;
        #pragma unroll
        for (int j = 0; j < 4; j++) {
            val[j] = acc[j] * inv + res[j];
            const int c = c0 + j;
            if (c < 32) {
                atomicAdd(&part[c], val[j]);
                atomicAdd(&part[32 + c], val[j] * val[j]);
            } else {
                atomicAdd(&part[64 + (c - 32) / 3], val[j] * val[j]);
            }
        }
        *(f32x4*)(out + (size_t)n * 56 + c0) = val;
    }
    __syncthreads();
    if (tid < 72) unsafeAtomicAdd(&stats[tid], part[tid]);
}

__global__ __launch_bounds__(256) void node_norm(
    float* __restrict__ out, const float* __restrict__ stats,
    const float* __restrict__ g0, const float* __restrict__ b0,
    const float* __restrict__ g1)
{
    const int id = blockIdx.x * 256 + threadIdx.x;
    if (id >= NNODE * 56) return;
    const int c = id % 56;
    float val = out[id];
    if (c < 32) {
        const float m   = stats[c]      * (1.0f / NNODE);
        const float ex2 = stats[32 + c] * (1.0f / NNODE);
        const float var = ex2 - m * m;
        val = (val - m) * rsqrtf(var + 1e-5f) * g0[c] + b0[c];
    } else {
        const int v = (c - 32) / 3;
        const float vn = stats[64 + v] * (1.0f / (3.0f * NNODE));
        val = val * rsqrtf(vn + 1e-5f) * g1[v];
    }
    out[id] = val;
}

extern "C" void kernel_launch(void* const* d_in, const int* in_sizes, int n_in,
                              void* d_out, int out_size, void* d_ws, size_t ws_size,
                              hipStream_t stream) {
    const float* node_attr = (const float*)d_in[0];
    const float* edge_attr = (const float*)d_in[1];
    const float* edge_sh   = (const float*)d_in[2];
    const int*   edge_index= (const int*)  d_in[3];
    const float* fc1_w     = (const float*)d_in[4];
    const float* fc1_b     = (const float*)d_in[5];
    const float* fc2_w     = (const float*)d_in[6];
    const float* fc2_b     = (const float*)d_in[7];
    const float* g0        = (const float*)d_in[8];
    const float* b0        = (const float*)d_in[9];
    const float* g1        = (const float*)d_in[10];
    float* out = (float*)d_out;

    char* ws = (char*)d_ws;
    // stats@0 288 | hist@288 40000 | offsets@40288 40032 | cursor@80320 40000 |
    // perm@120320 400000 | fc1_wt@520320 8192 | fc2_wt@528512 204800 | tp_out@733312
    float* stats   = (float*)(ws + 0);
    int*   hist    = (int*)  (ws + 288);
    int*   offsets = (int*)  (ws + 40288);
    int*   cursor  = (int*)  (ws + 80320);
    int*   perm    = (int*)  (ws + 120320);
    short* fc1_wt  = (short*)(ws + 520320);
    short* fc2_wt  = (short*)(ws + 528512);
    float* tp_out  = (float*)(ws + 733312);

    const bool csr = (ws_size >= 733312ull + 100000ull * 64 * 4);   // 26.33 MB

    hipMemsetAsync(ws, 0, 40288, stream);   // stats + hist
    if (csr) {
        prep<<<417, 256, 0, stream>>>(fc1_w, fc2_w, edge_index, fc1_wt, fc2_wt, hist);
        scan_hist<<<1, 256, 0, stream>>>(hist, offsets, cursor);
        edge_fused<true><<<782, 512, 0, stream>>>(node_attr, edge_attr, edge_sh, edge_index,
                                                  fc1_b, fc2_b, fc1_wt, fc2_wt, tp_out, cursor);
        node_agg<false><<<625, 256, 0, stream>>>(tp_out, offsets, nullptr, node_attr, out, stats);
    } else {
        prep<<<26, 256, 0, stream>>>(fc1_w, fc2_w, edge_index, fc1_wt, fc2_wt, hist);
        edge_fused<false><<<782, 512, 0, stream>>>(node_attr, edge_attr, edge_sh, edge_index,
                                                   fc1_b, fc2_b, fc1_wt, fc2_wt, tp_out, hist);
        scan_hist<<<1, 256, 0, stream>>>(hist, offsets, cursor);
        fill_perm<<<391, 256, 0, stream>>>(edge_index, cursor, perm);
        node_agg<true><<<625, 256, 0, stream>>>(tp_out, offsets, perm, node_attr, out, stats);
    }
    node_norm<<<2188, 256, 0, stream>>>(out, stats, g0, b0, g1);
}

// Round 12
// 104.992 us; speedup vs baseline: 1.0003x; 1.0003x over previous
//
#include <hip/hip_runtime.h>

typedef __attribute__((ext_vector_type(4)))  float f32x4;
typedef __attribute__((ext_vector_type(16))) float f32x16;
typedef __attribute__((ext_vector_type(8)))  short bf16x8;
typedef __attribute__((ext_vector_type(4)))  short short4v;

#define NEDGE 100000
#define NNODE 10000
#define INV40f 0.15811388300841897f
#define INV120f 0.09128709291752769f

__device__ inline short f2bf(float f) {
    unsigned u = __builtin_bit_cast(unsigned, f);
    u = (u + 0x7fffu + ((u >> 16) & 1u)) >> 16;
    return (short)u;
}

__device__ __forceinline__ float bperm(int byteIdx, float v) {
    return __builtin_bit_cast(float,
        __builtin_amdgcn_ds_bpermute(byteIdx, __builtin_bit_cast(int, v)));
}

__device__ __forceinline__ void stage16(const void* gsrc, void* ldst) {
    __builtin_amdgcn_global_load_lds(
        (const __attribute__((address_space(1))) unsigned*)gsrc,
        (__attribute__((address_space(3))) unsigned*)(unsigned long long)(uintptr_t)ldst,
        16, 0, 0);
}

#define MFMA32(A,B,C) __builtin_amdgcn_mfma_f32_32x32x16_bf16((A),(B),(C),0,0,0)

// prep: fc2_w [64k][1600c] -> fc2_wt [c][k] bf16 via LDS transpose; fc1_w -> fc1_wt; zero stats+hist
__global__ __launch_bounds__(256) void prep(const float* __restrict__ fc1_w,
                                            const float* __restrict__ fc2_w,
                                            short* __restrict__ fc1_wt,
                                            short* __restrict__ fc2_wt,
                                            float* __restrict__ stats,
                                            int* __restrict__ hist) {
    const int b = blockIdx.x, t = threadIdx.x;
    if (b < 25) {
        __shared__ short tile[64 * 66];
        const int c0 = b * 64;
        #pragma unroll
        for (int rep = 0; rep < 16; rep++) {
            const int idx = rep * 256 + t;
            const int k = idx >> 6, c = idx & 63;
            tile[k * 66 + c] = f2bf(fc2_w[(size_t)k * 1600 + c0 + c]);
        }
        __syncthreads();
        #pragma unroll
        for (int rep = 0; rep < 16; rep++) {
            const int idx = rep * 256 + t;
            const int c = idx >> 6, k = idx & 63;
            fc2_wt[(size_t)(c0 + c) * 64 + k] = tile[k * 66 + c];
        }
    } else if (b == 25) {
        #pragma unroll
        for (int rep = 0; rep < 16; rep++) {
            const int i = rep * 256 + t;
            fc1_wt[(i & 63) * 64 + (i >> 6)] = f2bf(fc1_w[i]);
        }
    } else if (b == 26) {
        if (t < 72) stats[t] = 0.0f;
    } else {
        const int i = (b - 27) * 256 + t;
        if (i < NNODE) hist[i] = 0;
    }
}

// 4 waves/block, 32 edges/wave via 32x32x16 MFMA (D: col=lane&31=edge, row=(reg&3)+8*(reg>>2)+4*half).
// fc2_wt staged in LDS: 13 x 16KB chunks (4 col-groups of 32 each), dbuf, XOR-swizzled.
__global__ __launch_bounds__(256, 2) void edge_fused(
    const float* __restrict__ node_attr,
    const float* __restrict__ edge_attr,
    const float* __restrict__ edge_sh,
    const int*   __restrict__ edge_index,
    const float* __restrict__ fc1_b,
    const float* __restrict__ fc2_b,
    const short* __restrict__ fc1_wt,
    const short* __restrict__ fc2_wt,
    float* __restrict__ tp_out,
    int*   __restrict__ hist)
{
    // LDS: cbA 16384 @0 | cbB 16384 @16384 (h_s alias: wid*4096) | shb 4x512 @32768 | bias 6400 @34816
    __shared__ __align__(16) char lds[41216];
    char* cbA = lds;
    char* cbB = lds + 16384;
    float* bias_s = (float*)(lds + 34816);

    const int tid  = threadIdx.x;
    const int wid  = tid >> 6;          // 0..3
    const int wtid = tid & 63;
    const int l31  = wtid & 31;
    const int half = wtid >> 5;
    const int e0   = blockIdx.x * 128 + wid * 32;
    const bool active = (e0 < NEDGE);   // NEDGE % 32 == 0: whole waves

    char*  h_s = cbB + wid * 4096;      // [32 edges][64 hid] bf16, swizzled; dead before phase-1 DMA
    float* shb = (float*)(lds + 32768 + wid * 512);
    const int swzl = (l31 & 7) << 4;

#define STAGE1(CH, BUF, J) do { \
        const int _o = (wid * 4 + (J)) * 1024 + wtid * 16; \
        const int _g = _o ^ (((_o >> 7) & 7) << 4); \
        stage16((const char*)fc2_wt + (CH) * 16384 + _g, (BUF) + (wid * 4 + (J)) * 1024); \
    } while (0)
#define STAGE_FULL(CH, BUF) do { STAGE1(CH,BUF,0); STAGE1(CH,BUF,1); STAGE1(CH,BUF,2); STAGE1(CH,BUF,3); } while (0)

    STAGE_FULL(0, cbA);   // chunk 0 in flight; overlaps prologue (cbA untouched below)

    // ---- bias -> LDS (400 f32x4) ----
    *(f32x4*)(bias_s + tid * 4) = *(const f32x4*)(fc2_b + tid * 4);
    if (tid < 144)
        *(f32x4*)(bias_s + (tid + 256) * 4) = *(const f32x4*)(fc2_b + (tid + 256) * 4);

    // ---- edge meta: lanes 0..31 own one edge ----
    int dst_r = 0;
    if (active && wtid < 32) {
        dst_r = edge_index[NEDGE + e0 + wtid];
        atomicAdd(&hist[edge_index[e0 + wtid]], 1);
        *(f32x4*)(shb + wtid * 4) = *(const f32x4*)(edge_sh + (size_t)(e0 + wtid) * 4);
    }

    bf16x8 hb[4];
    f32x4 shv = {0.f, 0.f, 0.f, 0.f};
    float cb1r[16], c10r[12], c11r[4];
    int vs[2];
    vs[0] = l31 * 4;
    vs[1] = (32 + l31) * 4;

    if (active) {
        const int dstm = __shfl(dst_r, l31, 64);
        const float* nap = node_attr + (size_t)dstm * 56;
        shv = *(const f32x4*)(shb + l31 * 4);   // same-wave LDS RAW, in-order

        // x0 slice u = half*16 .. +15  -> cb1r (c00 = shv0 * cb1, derived at consume)
        const f32x4 t0 = *(const f32x4*)(nap + half * 16);
        const f32x4 t1 = *(const f32x4*)(nap + half * 16 + 4);
        const f32x4 t2 = *(const f32x4*)(nap + half * 16 + 8);
        const f32x4 t3 = *(const f32x4*)(nap + half * 16 + 12);
        #pragma unroll
        for (int j = 0; j < 4; j++) {
            cb1r[j]      = INV40f * t0[j];
            cb1r[4 + j]  = INV40f * t1[j];
            cb1r[8 + j]  = INV40f * t2[j];
            cb1r[12 + j] = INV40f * t3[j];
        }
        // x1 slice u = half*4 .. +3 (12 floats at nap+32+half*12)
        const f32x4 y0 = *(const f32x4*)(nap + 32 + half * 12);
        const f32x4 y1 = *(const f32x4*)(nap + 32 + half * 12 + 4);
        const f32x4 y2 = *(const f32x4*)(nap + 32 + half * 12 + 8);
        float xx[12];
        #pragma unroll
        for (int j = 0; j < 4; j++) { xx[j] = y0[j]; xx[4 + j] = y1[j]; xx[8 + j] = y2[j]; }
        const float i40s0 = INV40f * shv[0];
        #pragma unroll
        for (int k = 0; k < 12; k++) c10r[k] = i40s0 * xx[k];
        #pragma unroll
        for (int e = 0; e < 4; e++)
            c11r[e] = INV120f * (xx[e*3]*shv[1] + xx[e*3+1]*shv[2] + xx[e*3+2]*shv[3]);

        // ---- fc1: h = relu(ea @ fc1_w + b) with 32x32x16 MFMA ----
        const float* pe = edge_attr + (size_t)(e0 + l31) * 64 + half * 8;
        bf16x8 eb[4];
        #pragma unroll
        for (int s = 0; s < 4; s++) {
            const f32x4 a = *(const f32x4*)(pe + s * 16);
            const f32x4 b = *(const f32x4*)(pe + s * 16 + 4);
            #pragma unroll
            for (int i = 0; i < 4; i++) { eb[s][i] = f2bf(a[i]); eb[s][4 + i] = f2bf(b[i]); }
        }
        #pragma unroll
        for (int g = 0; g < 2; g++) {
            f32x16 c;
            #pragma unroll
            for (int q = 0; q < 4; q++) {
                const f32x4 bq = *(const f32x4*)(fc1_b + g*32 + q*8 + half*4);
                c[q*4+0] = bq[0]; c[q*4+1] = bq[1]; c[q*4+2] = bq[2]; c[q*4+3] = bq[3];
            }
            #pragma unroll
            for (int s = 0; s < 4; s++) {
                const bf16x8 af = *(const bf16x8*)(fc1_wt + (g*32 + l31)*64 + s*16 + half*8);
                c = MFMA32(af, eb[s], c);
            }
            #pragma unroll
            for (int q = 0; q < 4; q++) {
                short4v p;
                #pragma unroll
                for (int j = 0; j < 4; j++) p[j] = f2bf(fmaxf(c[q*4+j], 0.0f));
                // hid = g*32 + q*8 + 4*half + j  (4 contiguous) -> 8B write
                *(short4v*)(h_s + (l31*128 + ((g*64 + q*16 + half*8) ^ swzl)));
                *(short4v*)(h_s + (l31*128 + ((g*64 + q*16 + half*8) ^ swzl))) = p;
            }
        }
        // read back B-frags: h[edge=l31][k = s*16 + half*8 + 0..7]
        #pragma unroll
        for (int s = 0; s < 4; s++)
            hb[s] = *(const bf16x8*)(h_s + (l31*128 + ((s*32 + half*16) ^ swzl)));
    }

    // ---- fc2 + TP consume ----
    float acc0[16] = {};
    float ab1[4] = {0,0,0,0};
    float b2[12] = {};

    auto mload = [&](const char* cb, int go, int G) -> f32x16 {
        f32x16 c;
        #pragma unroll
        for (int q = 0; q < 4; q++) {
            const f32x4 bq = *(const f32x4*)(bias_s + G*32 + q*8 + half*4);
            c[q*4+0] = bq[0]; c[q*4+1] = bq[1]; c[q*4+2] = bq[2]; c[q*4+3] = bq[3];
        }
        #pragma unroll
        for (int s = 0; s < 4; s++) {
            const bf16x8 a = *(const bf16x8*)(cb + go*4096 + l31*128 + ((s*32 + half*16) ^ swzl));
            c = MFMA32(a, hb[s], c);
        }
        return c;
    };

    auto cons_w00 = [&](const char* cb, int ch) {
        #pragma unroll
        for (int go = 0; go < 4; go++) {
            const int G = ch * 4 + go;                  // u = G
            const f32x16 c = mload(cb, go, G);
            const float cv = shv[0] * bperm(vs[G >> 4], cb1r[G & 15]);
            #pragma unroll
            for (int r = 0; r < 16; r++) acc0[r] += cv * c[r];
        }
    };
    auto cons_w01 = [&](const char* cb, int Gl0) {
        #pragma unroll
        for (int go = 0; go < 4; go++) {
            const int Gl = Gl0 + go;                    // 0..7
            const f32x16 c = mload(cb, go, 32 + Gl);
            #pragma unroll
            for (int q = 0; q < 4; q++) {
                const int u = Gl * 4 + q;               // 0..31
                const float cvq = bperm(vs[u >> 4], cb1r[u & 15]);
                #pragma unroll
                for (int j = 0; j < 4; j++) ab1[j] += cvq * c[q*4+j];
            }
        }
    };
    auto cons_w10 = [&](const char* cb) {
        #pragma unroll
        for (int go = 0; go < 2; go++) {
            const f32x16 c = mload(cb, go, 40 + go);
            #pragma unroll
            for (int q = 0; q < 4; q++) {
                const int u = go * 4 + q;               // 0..7
                #pragma unroll
                for (int i = 0; i < 3; i++) {
                    const float cv = bperm(vs[u >> 2], c10r[(u & 3) * 3 + i]);
                    #pragma unroll
                    for (int j = 0; j < 4; j++) b2[j*3+i] += cv * c[q*4+j];
                }
            }
        }
    };
    auto cons_w11_2 = [&](const char* cb, int goBase, int Gl0) {
        #pragma unroll
        for (int go = 0; go < 2; go++) {
            const int Gl = Gl0 + go;                    // u = Gl (0..7)
            const f32x16 c = mload(cb, goBase + go, 42 + Gl);
            const float cv = bperm(vs[Gl >> 2], c11r[Gl & 3]);
            #pragma unroll
            for (int r = 0; r < 16; r++) acc0[r] += cv * c[r];
        }
    };
    auto cons_w11_4 = [&](const char* cb, int Gl0) {
        #pragma unroll
        for (int go = 0; go < 4; go++) {
            const int Gl = Gl0 + go;
            const f32x16 c = mload(cb, go, 42 + Gl);
            const float cv = bperm(vs[Gl >> 2], c11r[Gl & 3]);
            #pragma unroll
            for (int r = 0; r < 16; r++) acc0[r] += cv * c[r];
        }
    };

    // ---- 13-phase chunk pipeline (chunk = 4 col-groups of 32) ----
    __syncthreads();                                   // chunk 0 + bias ready; h reads done
    STAGE_FULL(1,  cbB); if (active) cons_w00(cbA, 0); __syncthreads();
    STAGE_FULL(2,  cbA); if (active) cons_w00(cbB, 1); __syncthreads();
    STAGE_FULL(3,  cbB); if (active) cons_w00(cbA, 2); __syncthreads();
    STAGE_FULL(4,  cbA); if (active) cons_w00(cbB, 3); __syncthreads();
    STAGE_FULL(5,  cbB); if (active) cons_w00(cbA, 4); __syncthreads();
    STAGE_FULL(6,  cbA); if (active) cons_w00(cbB, 5); __syncthreads();
    STAGE_FULL(7,  cbB); if (active) cons_w00(cbA, 6); __syncthreads();
    STAGE_FULL(8,  cbA); if (active) cons_w00(cbB, 7); __syncthreads();
    STAGE_FULL(9,  cbB); if (active) cons_w01(cbA, 0); __syncthreads();
    STAGE_FULL(10, cbA); if (active) cons_w01(cbB, 4); __syncthreads();
    STAGE_FULL(11, cbB); if (active) { cons_w10(cbA); cons_w11_2(cbA, 2, 0); } __syncthreads();
    STAGE_FULL(12, cbA); if (active) cons_w11_4(cbB, 2); __syncthreads();
                         if (active) cons_w11_2(cbA, 0, 6);

    if (!active) return;

    // ---- emit: each lane owns full (edge=l31, w-subset) results; no reductions ----
    float* orow = tp_out + (size_t)(e0 + l31) * 56;
    #pragma unroll
    for (int q = 0; q < 4; q++)
        *(f32x4*)(orow + q*8 + half*4) = f32x4{acc0[q*4], acc0[q*4+1], acc0[q*4+2], acc0[q*4+3]};
    float ov[12];
    #pragma unroll
    for (int j = 0; j < 4; j++) {
        ov[j*3 + 0] = shv[1] * ab1[j] + b2[j*3 + 0];
        ov[j*3 + 1] = shv[2] * ab1[j] + b2[j*3 + 1];
        ov[j*3 + 2] = shv[3] * ab1[j] + b2[j*3 + 2];
    }
    float* p1 = orow + 32 + half * 12;
    *(f32x4*)(p1)     = f32x4{ov[0], ov[1], ov[2],  ov[3]};
    *(f32x4*)(p1 + 4) = f32x4{ov[4], ov[5], ov[6],  ov[7]};
    *(f32x4*)(p1 + 8) = f32x4{ov[8], ov[9], ov[10], ov[11]};
#undef STAGE1
#undef STAGE_FULL
}

// exclusive prefix scan of hist[10000] -> offsets[10001], cursor (wave-shuffle scan)
__global__ __launch_bounds__(256) void scan_hist(const int* __restrict__ hist,
                                                 int* __restrict__ offsets,
                                                 int* __restrict__ cursor) {
    __shared__ int wsum[4];
    const int t = threadIdx.x;
    const int lane = t & 63;
    const int w = t >> 6;
    const int n0 = t * 40;
    int s = 0;
    if (n0 < NNODE) {
        for (int j = 0; j < 40; j++) s += hist[n0 + j];
    }
    int incl = s;
    #pragma unroll
    for (int d = 1; d < 64; d <<= 1) {
        const int v = __shfl_up(incl, d, 64);
        if (lane >= d) incl += v;
    }
    if (lane == 63) wsum[w] = incl;
    __syncthreads();
    int base = 0;
    for (int ww = 0; ww < 4; ww++) base += (ww < w) ? wsum[ww] : 0;
    if (n0 < NNODE) {
        int run = base + incl - s;
        for (int j = 0; j < 40; j++) {
            const int h = hist[n0 + j];
            offsets[n0 + j] = run; cursor[n0 + j] = run; run += h;
        }
    }
    if (t == 0) offsets[NNODE] = NEDGE;
}

__global__ __launch_bounds__(256) void fill_perm(const int* __restrict__ edge_index,
                                                 int* __restrict__ cursor,
                                                 int* __restrict__ perm) {
    const int e = blockIdx.x * 256 + threadIdx.x;
    if (e < NEDGE) {
        const int s = edge_index[e];
        const int p = atomicAdd(&cursor[s], 1);
        perm[p] = e;
    }
}

// gather-based segment mean + residual + BN partial stats
__global__ __launch_bounds__(256) void node_agg(
    const float* __restrict__ tp_out, const int* __restrict__ offsets,
    const int* __restrict__ perm,
    const float* __restrict__ node_attr, float* __restrict__ out,
    float* __restrict__ stats)
{
    __shared__ float part[72];
    const int tid = threadIdx.x;
    if (tid < 72) part[tid] = 0.0f;
    __syncthreads();
    const int n = blockIdx.x * 16 + (tid >> 4);
    const int q = tid & 15;
    if (n < NNODE && q < 14) {
        const int st = offsets[n], en = offsets[n + 1];
        f32x4 acc = {0.f, 0.f, 0.f, 0.f};
        for (int r = st; r < en; r++)
            acc += *(const f32x4*)(tp_out + (size_t)perm[r] * 56 + q * 4);
        const float inv = 1.0f / fmaxf((float)(en - st), 1.0f);
        const int c0 = q * 4;
        const f32x4 res = *(const f32x4*)(node_attr + (size_t)n * 56 + c0);
        f32x4 val;
        #pragma unroll
        for (int j = 0; j < 4; j++) {
            val[j] = acc[j] * inv + res[j];
            const int c = c0 + j;
            if (c < 32) {
                atomicAdd(&part[c], val[j]);
                atomicAdd(&part[32 + c], val[j] * val[j]);
            } else {
                atomicAdd(&part[64 + (c - 32) / 3], val[j] * val[j]);
            }
        }
        *(f32x4*)(out + (size_t)n * 56 + c0) = val;
    }
    __syncthreads();
    if (tid < 72) unsafeAtomicAdd(&stats[tid], part[tid]);
}

__global__ __launch_bounds__(256) void node_norm(
    float* __restrict__ out, const float* __restrict__ stats,
    const float* __restrict__ g0, const float* __restrict__ b0,
    const float* __restrict__ g1)
{
    const int id = blockIdx.x * 256 + threadIdx.x;
    if (id >= NNODE * 56) return;
    const int c = id % 56;
    float val = out[id];
    if (c < 32) {
        const float m   = stats[c]      * (1.0f / NNODE);
        const float ex2 = stats[32 + c] * (1.0f / NNODE);
        const float var = ex2 - m * m;
        val = (val - m) * rsqrtf(var + 1e-5f) * g0[c] + b0[c];
    } else {
        const int v = (c - 32) / 3;
        const float vn = stats[64 + v] * (1.0f / (3.0f * NNODE));
        val = val * rsqrtf(vn + 1e-5f) * g1[v];
    }
    out[id] = val;
}

extern "C" void kernel_launch(void* const* d_in, const int* in_sizes, int n_in,
                              void* d_out, int out_size, void* d_ws, size_t ws_size,
                              hipStream_t stream) {
    const float* node_attr = (const float*)d_in[0];
    const float* edge_attr = (const float*)d_in[1];
    const float* edge_sh   = (const float*)d_in[2];
    const int*   edge_index= (const int*)  d_in[3];
    const float* fc1_w     = (const float*)d_in[4];
    const float* fc1_b     = (const float*)d_in[5];
    const float* fc2_w     = (const float*)d_in[6];
    const float* fc2_b     = (const float*)d_in[7];
    const float* g0        = (const float*)d_in[8];
    const float* b0        = (const float*)d_in[9];
    const float* g1        = (const float*)d_in[10];
    float* out = (float*)d_out;

    char* ws = (char*)d_ws;
    float* stats   = (float*)(ws + 0);
    int*   hist    = (int*)  (ws + 288);
    int*   offsets = (int*)  (ws + 40288);
    int*   cursor  = (int*)  (ws + 80320);
    int*   perm    = (int*)  (ws + 120320);
    short* fc1_wt  = (short*)(ws + 520320);
    short* fc2_wt  = (short*)(ws + 528512);
    float* tp_out  = (float*)(ws + 733312);

    prep<<<67, 256, 0, stream>>>(fc1_w, fc2_w, fc1_wt, fc2_wt, stats, hist);
    edge_fused<<<782, 256, 0, stream>>>(node_attr, edge_attr, edge_sh, edge_index,
                                        fc1_b, fc2_b, fc1_wt, fc2_wt, tp_out, hist);
    scan_hist<<<1, 256, 0, stream>>>(hist, offsets, cursor);
    fill_perm<<<391, 256, 0, stream>>>(edge_index, cursor, perm);
    node_agg<<<625, 256, 0, stream>>>(tp_out, offsets, perm, node_attr, out, stats);
    node_norm<<<2188, 256, 0, stream>>>(out, stats, g0, b0, g1);
}

// Round 13
// 103.989 us; speedup vs baseline: 1.0100x; 1.0096x over previous
//
#include <hip/hip_runtime.h>

typedef __attribute__((ext_vector_type(4)))  float f32x4;
typedef __attribute__((ext_vector_type(16))) float f32x16;
typedef __attribute__((ext_vector_type(8)))  short bf16x8;
typedef __attribute__((ext_vector_type(4)))  short short4v;

#define NEDGE 100000
#define NNODE 10000
#define INV40f 0.15811388300841897f
#define INV120f 0.09128709291752769f

__device__ inline short f2bf(float f) {
    unsigned u = __builtin_bit_cast(unsigned, f);
    u = (u + 0x7fffu + ((u >> 16) & 1u)) >> 16;
    return (short)u;
}

__device__ __forceinline__ float bperm(int byteIdx, float v) {
    return __builtin_bit_cast(float,
        __builtin_amdgcn_ds_bpermute(byteIdx, __builtin_bit_cast(int, v)));
}

__device__ __forceinline__ void stage16(const void* gsrc, void* ldst) {
    __builtin_amdgcn_global_load_lds(
        (const __attribute__((address_space(1))) unsigned*)gsrc,
        (__attribute__((address_space(3))) unsigned*)(unsigned long long)(uintptr_t)ldst,
        16, 0, 0);
}

#define MFMA32(A,B,C) __builtin_amdgcn_mfma_f32_32x32x16_bf16((A),(B),(C),0,0,0)

// prep: fc2_w [64k][1600c] -> fc2_wt [c][k] bf16 via LDS transpose; fc1_w -> fc1_wt; zero stats+hist
__global__ __launch_bounds__(256) void prep(const float* __restrict__ fc1_w,
                                            const float* __restrict__ fc2_w,
                                            short* __restrict__ fc1_wt,
                                            short* __restrict__ fc2_wt,
                                            float* __restrict__ stats,
                                            int* __restrict__ hist) {
    const int b = blockIdx.x, t = threadIdx.x;
    if (b < 25) {
        __shared__ short tile[64 * 66];
        const int c0 = b * 64;
        #pragma unroll
        for (int rep = 0; rep < 16; rep++) {
            const int idx = rep * 256 + t;
            const int k = idx >> 6, c = idx & 63;
            tile[k * 66 + c] = f2bf(fc2_w[(size_t)k * 1600 + c0 + c]);
        }
        __syncthreads();
        #pragma unroll
        for (int rep = 0; rep < 16; rep++) {
            const int idx = rep * 256 + t;
            const int c = idx >> 6, k = idx & 63;
            fc2_wt[(size_t)(c0 + c) * 64 + k] = tile[k * 66 + c];
        }
    } else if (b == 25) {
        #pragma unroll
        for (int rep = 0; rep < 16; rep++) {
            const int i = rep * 256 + t;
            fc1_wt[(i & 63) * 64 + (i >> 6)] = f2bf(fc1_w[i]);
        }
    } else if (b == 26) {
        if (t < 72) stats[t] = 0.0f;
    } else {
        const int i = (b - 27) * 256 + t;
        if (i < NNODE) hist[i] = 0;
    }
}

// 4 waves/block, 32 edges/wave via 32x32x16 MFMA.
// fc2_wt staged through THREE 16KB LDS buffers with counted vmcnt (never 0 in steady state):
// phase k: waitcnt vmcnt(8); s_barrier; consume(b[k%3]); s_barrier; STAGE(c_{k+3} -> b[k%3]).
__global__ __launch_bounds__(256, 2) void edge_fused(
    const float* __restrict__ node_attr,
    const float* __restrict__ edge_attr,
    const float* __restrict__ edge_sh,
    const int*   __restrict__ edge_index,
    const float* __restrict__ fc1_b,
    const float* __restrict__ fc2_b,
    const short* __restrict__ fc1_wt,
    const short* __restrict__ fc2_wt,
    float* __restrict__ tp_out,
    int*   __restrict__ hist)
{
    // LDS: b0 @0 | b1 @16384 | b2 @32768 (h_s alias) | shb @49152 (2048) | bias @51200 (6400)
    __shared__ __align__(16) char lds[57600];
    char* bufs0 = lds;
    char* bufs1 = lds + 16384;
    char* bufs2 = lds + 32768;
    float* bias_s = (float*)(lds + 51200);

    const int tid  = threadIdx.x;
    const int wid  = tid >> 6;          // 0..3
    const int wtid = tid & 63;
    const int l31  = wtid & 31;
    const int half = wtid >> 5;
    const int e0   = blockIdx.x * 128 + wid * 32;
    const bool active = (e0 < NEDGE);   // NEDGE % 32 == 0: whole waves

    char*  h_s = bufs2 + wid * 4096;    // [32 edges][64 hid] bf16 swizzled; dead before c2 DMA lands
    float* shb = (float*)(lds + 49152 + wid * 512);
    const int swzl = (l31 & 7) << 4;

#define STAGE1(CH, BUF, J) do { \
        const int _o = (wid * 4 + (J)) * 1024 + wtid * 16; \
        const int _g = _o ^ (((_o >> 7) & 7) << 4); \
        stage16((const char*)fc2_wt + (CH) * 16384 + _g, (BUF) + (wid * 4 + (J)) * 1024); \
    } while (0)
#define STAGE_FULL(CH, BUF) do { STAGE1(CH,BUF,0); STAGE1(CH,BUF,1); STAGE1(CH,BUF,2); STAGE1(CH,BUF,3); } while (0)

    // ---- prologue: ALL global loads + LDS writes happen here (drained before stages) ----

    // bias -> LDS (400 f32x4)
    *(f32x4*)(bias_s + tid * 4) = *(const f32x4*)(fc2_b + tid * 4);
    if (tid < 144)
        *(f32x4*)(bias_s + (tid + 256) * 4) = *(const f32x4*)(fc2_b + (tid + 256) * 4);

    // edge meta: lanes 0..31 own one edge
    int dst_r = 0;
    if (active && wtid < 32) {
        dst_r = edge_index[NEDGE + e0 + wtid];
        atomicAdd(&hist[edge_index[e0 + wtid]], 1);
        *(f32x4*)(shb + wtid * 4) = *(const f32x4*)(edge_sh + (size_t)(e0 + wtid) * 4);
    }

    bf16x8 hb[4];
    f32x4 shv = {0.f, 0.f, 0.f, 0.f};
    float cb1r[16], c10r[12], c11r[4];
    int vs[2];
    vs[0] = l31 * 4;
    vs[1] = (32 + l31) * 4;

    if (active) {
        const int dstm = __shfl(dst_r, l31, 64);
        const float* nap = node_attr + (size_t)dstm * 56;
        shv = *(const f32x4*)(shb + l31 * 4);   // same-wave LDS RAW, in-order

        const f32x4 t0 = *(const f32x4*)(nap + half * 16);
        const f32x4 t1 = *(const f32x4*)(nap + half * 16 + 4);
        const f32x4 t2 = *(const f32x4*)(nap + half * 16 + 8);
        const f32x4 t3 = *(const f32x4*)(nap + half * 16 + 12);
        #pragma unroll
        for (int j = 0; j < 4; j++) {
            cb1r[j]      = INV40f * t0[j];
            cb1r[4 + j]  = INV40f * t1[j];
            cb1r[8 + j]  = INV40f * t2[j];
            cb1r[12 + j] = INV40f * t3[j];
        }
        const f32x4 y0 = *(const f32x4*)(nap + 32 + half * 12);
        const f32x4 y1 = *(const f32x4*)(nap + 32 + half * 12 + 4);
        const f32x4 y2 = *(const f32x4*)(nap + 32 + half * 12 + 8);
        float xx[12];
        #pragma unroll
        for (int j = 0; j < 4; j++) { xx[j] = y0[j]; xx[4 + j] = y1[j]; xx[8 + j] = y2[j]; }
        const float i40s0 = INV40f * shv[0];
        #pragma unroll
        for (int k = 0; k < 12; k++) c10r[k] = i40s0 * xx[k];
        #pragma unroll
        for (int e = 0; e < 4; e++)
            c11r[e] = INV120f * (xx[e*3]*shv[1] + xx[e*3+1]*shv[2] + xx[e*3+2]*shv[3]);

        // fc1: h = relu(ea @ fc1_w + b) with 32x32x16 MFMA -> swizzled wave-private LDS (in b2)
        const float* pe = edge_attr + (size_t)(e0 + l31) * 64 + half * 8;
        bf16x8 eb[4];
        #pragma unroll
        for (int s = 0; s < 4; s++) {
            const f32x4 a = *(const f32x4*)(pe + s * 16);
            const f32x4 b = *(const f32x4*)(pe + s * 16 + 4);
            #pragma unroll
            for (int i = 0; i < 4; i++) { eb[s][i] = f2bf(a[i]); eb[s][4 + i] = f2bf(b[i]); }
        }
        #pragma unroll
        for (int g = 0; g < 2; g++) {
            f32x16 c;
            #pragma unroll
            for (int q = 0; q < 4; q++) {
                const f32x4 bq = *(const f32x4*)(fc1_b + g*32 + q*8 + half*4);
                c[q*4+0] = bq[0]; c[q*4+1] = bq[1]; c[q*4+2] = bq[2]; c[q*4+3] = bq[3];
            }
            #pragma unroll
            for (int s = 0; s < 4; s++) {
                const bf16x8 af = *(const bf16x8*)(fc1_wt + (g*32 + l31)*64 + s*16 + half*8);
                c = MFMA32(af, eb[s], c);
            }
            #pragma unroll
            for (int q = 0; q < 4; q++) {
                short4v p;
                #pragma unroll
                for (int j = 0; j < 4; j++) p[j] = f2bf(fmaxf(c[q*4+j], 0.0f));
                *(short4v*)(h_s + (l31*128 + ((g*64 + q*16 + half*8) ^ swzl))) = p;
            }
        }
        // read back B-frags: h[edge=l31][k-slice]
        #pragma unroll
        for (int s = 0; s < 4; s++)
            hb[s] = *(const bf16x8*)(h_s + (l31*128 + ((s*32 + half*16) ^ swzl)));
    }

    // ---- drain LDS ops (h reads retired to regs; h/shb/bias writes flushed), sync waves ----
    asm volatile("s_waitcnt lgkmcnt(0)" ::: "memory");
    __builtin_amdgcn_sched_barrier(0);
    __builtin_amdgcn_s_barrier();
    __builtin_amdgcn_sched_barrier(0);

    // ---- prime the pipeline: 3 chunks in flight (12 loads/wave) ----
    STAGE_FULL(0, bufs0);
    STAGE_FULL(1, bufs1);
    STAGE_FULL(2, bufs2);

    // ---- fc2 + TP consume ----
    float acc0[16] = {};
    float ab1[4] = {0,0,0,0};
    float b2[12] = {};

    auto mload = [&](const char* cb, int go, int G) -> f32x16 {
        f32x16 c;
        #pragma unroll
        for (int q = 0; q < 4; q++) {
            const f32x4 bq = *(const f32x4*)(bias_s + G*32 + q*8 + half*4);
            c[q*4+0] = bq[0]; c[q*4+1] = bq[1]; c[q*4+2] = bq[2]; c[q*4+3] = bq[3];
        }
        #pragma unroll
        for (int s = 0; s < 4; s++) {
            const bf16x8 a = *(const bf16x8*)(cb + go*4096 + l31*128 + ((s*32 + half*16) ^ swzl));
            c = MFMA32(a, hb[s], c);
        }
        return c;
    };

    auto cons_w00 = [&](const char* cb, int ch) {
        #pragma unroll
        for (int go = 0; go < 4; go++) {
            const int G = ch * 4 + go;                  // u = G
            const f32x16 c = mload(cb, go, G);
            const float cv = shv[0] * bperm(vs[G >> 4], cb1r[G & 15]);
            #pragma unroll
            for (int r = 0; r < 16; r++) acc0[r] += cv * c[r];
        }
    };
    auto cons_w01 = [&](const char* cb, int Gl0) {
        #pragma unroll
        for (int go = 0; go < 4; go++) {
            const int Gl = Gl0 + go;                    // 0..7
            const f32x16 c = mload(cb, go, 32 + Gl);
            #pragma unroll
            for (int q = 0; q < 4; q++) {
                const int u = Gl * 4 + q;               // 0..31
                const float cvq = bperm(vs[u >> 4], cb1r[u & 15]);
                #pragma unroll
                for (int j = 0; j < 4; j++) ab1[j] += cvq * c[q*4+j];
            }
        }
    };
    auto cons_w10 = [&](const char* cb) {
        #pragma unroll
        for (int go = 0; go < 2; go++) {
            const f32x16 c = mload(cb, go, 40 + go);
            #pragma unroll
            for (int q = 0; q < 4; q++) {
                const int u = go * 4 + q;               // 0..7
                #pragma unroll
                for (int i = 0; i < 3; i++) {
                    const float cv = bperm(vs[u >> 2], c10r[(u & 3) * 3 + i]);
                    #pragma unroll
                    for (int j = 0; j < 4; j++) b2[j*3+i] += cv * c[q*4+j];
                }
            }
        }
    };
    auto cons_w11_2 = [&](const char* cb, int goBase, int Gl0) {
        #pragma unroll
        for (int go = 0; go < 2; go++) {
            const int Gl = Gl0 + go;                    // u = Gl (0..7)
            const f32x16 c = mload(cb, goBase + go, 42 + Gl);
            const float cv = bperm(vs[Gl >> 2], c11r[Gl & 3]);
            #pragma unroll
            for (int r = 0; r < 16; r++) acc0[r] += cv * c[r];
        }
    };
    auto cons_w11_4 = [&](const char* cb, int Gl0) {
        #pragma unroll
        for (int go = 0; go < 4; go++) {
            const int Gl = Gl0 + go;
            const f32x16 c = mload(cb, go, 42 + Gl);
            const float cv = bperm(vs[Gl >> 2], c11r[Gl & 3]);
            #pragma unroll
            for (int r = 0; r < 16; r++) acc0[r] += cv * c[r];
        }
    };

#define WAITBAR(N) do { \
        asm volatile("s_waitcnt vmcnt(" N ")" ::: "memory"); \
        __builtin_amdgcn_sched_barrier(0); \
        __builtin_amdgcn_s_barrier(); \
        __builtin_amdgcn_sched_barrier(0); \
    } while (0)
#define ENDPHASE() do { \
        __builtin_amdgcn_s_barrier(); \
        __builtin_amdgcn_sched_barrier(0); \
    } while (0)

    // ---- 13 phases; counted vmcnt keeps 2 chunks in flight across barriers ----
    WAITBAR("8"); if (active) cons_w00(bufs0, 0); ENDPHASE(); STAGE_FULL(3,  bufs0);
    WAITBAR("8"); if (active) cons_w00(bufs1, 1); ENDPHASE(); STAGE_FULL(4,  bufs1);
    WAITBAR("8"); if (active) cons_w00(bufs2, 2); ENDPHASE(); STAGE_FULL(5,  bufs2);
    WAITBAR("8"); if (active) cons_w00(bufs0, 3); ENDPHASE(); STAGE_FULL(6,  bufs0);
    WAITBAR("8"); if (active) cons_w00(bufs1, 4); ENDPHASE(); STAGE_FULL(7,  bufs1);
    WAITBAR("8"); if (active) cons_w00(bufs2, 5); ENDPHASE(); STAGE_FULL(8,  bufs2);
    WAITBAR("8"); if (active) cons_w00(bufs0, 6); ENDPHASE(); STAGE_FULL(9,  bufs0);
    WAITBAR("8"); if (active) cons_w00(bufs1, 7); ENDPHASE(); STAGE_FULL(10, bufs1);
    WAITBAR("8"); if (active) cons_w01(bufs2, 0); ENDPHASE(); STAGE_FULL(11, bufs2);
    WAITBAR("8"); if (active) cons_w01(bufs0, 4); ENDPHASE(); STAGE_FULL(12, bufs0);
    WAITBAR("8"); if (active) { cons_w10(bufs1); cons_w11_2(bufs1, 2, 0); } ENDPHASE();
    WAITBAR("4"); if (active) cons_w11_4(bufs2, 2); ENDPHASE();
    WAITBAR("0"); if (active) cons_w11_2(bufs0, 0, 6);

#undef WAITBAR
#undef ENDPHASE
#undef STAGE1
#undef STAGE_FULL

    if (!active) return;

    // ---- emit: each lane owns full (edge=l31, w-subset) results; no reductions ----
    float* orow = tp_out + (size_t)(e0 + l31) * 56;
    #pragma unroll
    for (int q = 0; q < 4; q++)
        *(f32x4*)(orow + q*8 + half*4) = f32x4{acc0[q*4], acc0[q*4+1], acc0[q*4+2], acc0[q*4+3]};
    float ov[12];
    #pragma unroll
    for (int j = 0; j < 4; j++) {
        ov[j*3 + 0] = shv[1] * ab1[j] + b2[j*3 + 0];
        ov[j*3 + 1] = shv[2] * ab1[j] + b2[j*3 + 1];
        ov[j*3 + 2] = shv[3] * ab1[j] + b2[j*3 + 2];
    }
    float* p1 = orow + 32 + half * 12;
    *(f32x4*)(p1)     = f32x4{ov[0], ov[1], ov[2],  ov[3]};
    *(f32x4*)(p1 + 4) = f32x4{ov[4], ov[5], ov[6],  ov[7]};
    *(f32x4*)(p1 + 8) = f32x4{ov[8], ov[9], ov[10], ov[11]};
}

// exclusive prefix scan of hist[10000] -> offsets[10001], cursor (wave-shuffle scan)
__global__ __launch_bounds__(256) void scan_hist(const int* __restrict__ hist,
                                                 int* __restrict__ offsets,
                                                 int* __restrict__ cursor) {
    __shared__ int wsum[4];
    const int t = threadIdx.x;
    const int lane = t & 63;
    const int w = t >> 6;
    const int n0 = t * 40;
    int s = 0;
    if (n0 < NNODE) {
        for (int j = 0; j < 40; j++) s += hist[n0 + j];
    }
    int incl = s;
    #pragma unroll
    for (int d = 1; d < 64; d <<= 1) {
        const int v = __shfl_up(incl, d, 64);
        if (lane >= d) incl += v;
    }
    if (lane == 63) wsum[w] = incl;
    __syncthreads();
    int base = 0;
    for (int ww = 0; ww < 4; ww++) base += (ww < w) ? wsum[ww] : 0;
    if (n0 < NNODE) {
        int run = base + incl - s;
        for (int j = 0; j < 40; j++) {
            const int h = hist[n0 + j];
            offsets[n0 + j] = run; cursor[n0 + j] = run; run += h;
        }
    }
    if (t == 0) offsets[NNODE] = NEDGE;
}

__global__ __launch_bounds__(256) void fill_perm(const int* __restrict__ edge_index,
                                                 int* __restrict__ cursor,
                                                 int* __restrict__ perm) {
    const int e = blockIdx.x * 256 + threadIdx.x;
    if (e < NEDGE) {
        const int s = edge_index[e];
        const int p = atomicAdd(&cursor[s], 1);
        perm[p] = e;
    }
}

// gather-based segment mean + residual + BN partial stats
__global__ __launch_bounds__(256) void node_agg(
    const float* __restrict__ tp_out, const int* __restrict__ offsets,
    const int* __restrict__ perm,
    const float* __restrict__ node_attr, float* __restrict__ out,
    float* __restrict__ stats)
{
    __shared__ float part[72];
    const int tid = threadIdx.x;
    if (tid < 72) part[tid] = 0.0f;
    __syncthreads();
    const int n = blockIdx.x * 16 + (tid >> 4);
    const int q = tid & 15;
    if (n < NNODE && q < 14) {
        const int st = offsets[n], en = offsets[n + 1];
        f32x4 acc = {0.f, 0.f, 0.f, 0.f};
        for (int r = st; r < en; r++)
            acc += *(const f32x4*)(tp_out + (size_t)perm[r] * 56 + q * 4);
        const float inv = 1.0f / fmaxf((float)(en - st), 1.0f);
        const int c0 = q * 4;
        const f32x4 res = *(const f32x4*)(node_attr + (size_t)n * 56 + c0);
        f32x4 val;
        #pragma unroll
        for (int j = 0; j < 4; j++) {
            val[j] = acc[j] * inv + res[j];
            const int c = c0 + j;
            if (c < 32) {
                atomicAdd(&part[c], val[j]);
                atomicAdd(&part[32 + c], val[j] * val[j]);
            } else {
                atomicAdd(&part[64 + (c - 32) / 3], val[j] * val[j]);
            }
        }
        *(f32x4*)(out + (size_t)n * 56 + c0) = val;
    }
    __syncthreads();
    if (tid < 72) unsafeAtomicAdd(&stats[tid], part[tid]);
}

__global__ __launch_bounds__(256) void node_norm(
    float* __restrict__ out, const float* __restrict__ stats,
    const float* __restrict__ g0, const float* __restrict__ b0,
    const float* __restrict__ g1)
{
    const int id = blockIdx.x * 256 + threadIdx.x;
    if (id >= NNODE * 56) return;
    const int c = id % 56;
    float val = out[id];
    if (c < 32) {
        const float m   = stats[c]      * (1.0f / NNODE);
        const float ex2 = stats[32 + c] * (1.0f / NNODE);
        const float var = ex2 - m * m;
        val = (val - m) * rsqrtf(var + 1e-5f) * g0[c] + b0[c];
    } else {
        const int v = (c - 32) / 3;
        const float vn = stats[64 + v] * (1.0f / (3.0f * NNODE));
        val = val * rsqrtf(vn + 1e-5f) * g1[v];
    }
    out[id] = val;
}

extern "C" void kernel_launch(void* const* d_in, const int* in_sizes, int n_in,
                              void* d_out, int out_size, void* d_ws, size_t ws_size,
                              hipStream_t stream) {
    const float* node_attr = (const float*)d_in[0];
    const float* edge_attr = (const float*)d_in[1];
    const float* edge_sh   = (const float*)d_in[2];
    const int*   edge_index= (const int*)  d_in[3];
    const float* fc1_w     = (const float*)d_in[4];
    const float* fc1_b     = (const float*)d_in[5];
    const float* fc2_w     = (const float*)d_in[6];
    const float* fc2_b     = (const float*)d_in[7];
    const float* g0        = (const float*)d_in[8];
    const float* b0        = (const float*)d_in[9];
    const float* g1        = (const float*)d_in[10];
    float* out = (float*)d_out;

    char* ws = (char*)d_ws;
    float* stats   = (float*)(ws + 0);
    int*   hist    = (int*)  (ws + 288);
    int*   offsets = (int*)  (ws + 40288);
    int*   cursor  = (int*)  (ws + 80320);
    int*   perm    = (int*)  (ws + 120320);
    short* fc1_wt  = (short*)(ws + 520320);
    short* fc2_wt  = (short*)(ws + 528512);
    float* tp_out  = (float*)(ws + 733312);

    prep<<<67, 256, 0, stream>>>(fc1_w, fc2_w, fc1_wt, fc2_wt, stats, hist);
    edge_fused<<<782, 256, 0, stream>>>(node_attr, edge_attr, edge_sh, edge_index,
                                        fc1_b, fc2_b, fc1_wt, fc2_wt, tp_out, hist);
    scan_hist<<<1, 256, 0, stream>>>(hist, offsets, cursor);
    fill_perm<<<391, 256, 0, stream>>>(edge_index, cursor, perm);
    node_agg<<<625, 256, 0, stream>>>(tp_out, offsets, perm, node_attr, out, stats);
    node_norm<<<2188, 256, 0, stream>>>(out, stats, g0, b0, g1);
}

// Round 14
// 101.287 us; speedup vs baseline: 1.0369x; 1.0267x over previous
//
#include <hip/hip_runtime.h>

typedef __attribute__((ext_vector_type(4)))  float f32x4;
typedef __attribute__((ext_vector_type(16))) float f32x16;
typedef __attribute__((ext_vector_type(8)))  short bf16x8;
typedef __attribute__((ext_vector_type(4)))  short short4v;

#define NEDGE 100000
#define NNODE 10000
#define INV40f 0.15811388300841897f
#define INV120f 0.09128709291752769f

__device__ inline short f2bf(float f) {
    unsigned u = __builtin_bit_cast(unsigned, f);
    u = (u + 0x7fffu + ((u >> 16) & 1u)) >> 16;
    return (short)u;
}

__device__ __forceinline__ float bperm(int byteIdx, float v) {
    return __builtin_bit_cast(float,
        __builtin_amdgcn_ds_bpermute(byteIdx, __builtin_bit_cast(int, v)));
}

__device__ __forceinline__ void stage16(const void* gsrc, void* ldst) {
    __builtin_amdgcn_global_load_lds(
        (const __attribute__((address_space(1))) unsigned*)gsrc,
        (__attribute__((address_space(3))) unsigned*)(unsigned long long)(uintptr_t)ldst,
        16, 0, 0);
}

#define MFMA32(A,B,C) __builtin_amdgcn_mfma_f32_32x32x16_bf16((A),(B),(C),0,0,0)

// prep: fc2_w [64k][1600c] -> fc2_wt in FRAGMENT-MAJOR layout:
//   short index = chunk*8192 + g2*2048 + t*256 + c*8 + j
//   (chunk: 128 cols; g2: col-group of 32; t = s*2+half; k = (t>>1)*16 + (t&1)*8 + j)
// so edge_fused stages with PURE LINEAR global reads and reads LDS conflict-free without swizzle.
__global__ __launch_bounds__(256) void prep(const float* __restrict__ fc1_w,
                                            const float* __restrict__ fc2_w,
                                            short* __restrict__ fc1_wt,
                                            short* __restrict__ fc2_wt,
                                            float* __restrict__ stats,
                                            int* __restrict__ hist) {
    const int b = blockIdx.x, t = threadIdx.x;
    if (b < 25) {
        __shared__ short tile[64 * 66];
        const int c0 = b * 64;                 // block b covers cols b*64 .. b*64+63
        #pragma unroll
        for (int rep = 0; rep < 16; rep++) {
            const int idx = rep * 256 + t;
            const int k = idx >> 6, c = idx & 63;
            tile[k * 66 + c] = f2bf(fc2_w[(size_t)k * 1600 + c0 + c]);
        }
        __syncthreads();
        // output shorts [b*4096, b*4096+4096): og -> (g2rel, t2, cl, j)
        short* outp = fc2_wt + b * 4096;
        #pragma unroll
        for (int rep = 0; rep < 16; rep++) {
            const int og = rep * 256 + t;      // 0..4095
            const int g2rel = og >> 11;
            const int t2 = (og >> 8) & 7;
            const int cl = ((og >> 3) & 31) + g2rel * 32;   // local col 0..63
            const int j = og & 7;
            const int k = (t2 >> 1) * 16 + (t2 & 1) * 8 + j;
            outp[og] = tile[k * 66 + cl];
        }
    } else if (b == 25) {
        #pragma unroll
        for (int rep = 0; rep < 16; rep++) {
            const int i = rep * 256 + t;
            fc1_wt[(i & 63) * 64 + (i >> 6)] = f2bf(fc1_w[i]);
        }
    } else if (b == 26) {
        if (t < 72) stats[t] = 0.0f;
    } else {
        const int i = (b - 27) * 256 + t;
        if (i < NNODE) hist[i] = 0;
    }
}

// 4 waves/block, 32 edges/wave via 32x32x16 MFMA. fc2_wt staged via LINEAR DMA
// (13 x 16KB chunks, dbuf); fragment-major layout makes ds_reads conflict-free unswizzled.
__global__ __launch_bounds__(256, 2) void edge_fused(
    const float* __restrict__ node_attr,
    const float* __restrict__ edge_attr,
    const float* __restrict__ edge_sh,
    const int*   __restrict__ edge_index,
    const float* __restrict__ fc1_b,
    const float* __restrict__ fc2_b,
    const short* __restrict__ fc1_wt,
    const short* __restrict__ fc2_wt,
    float* __restrict__ tp_out,
    int*   __restrict__ hist)
{
    // LDS: cbA 16384 @0 | cbB 16384 @16384 (h_s alias) | shb 4x512 @32768 | bias 6400 @34816
    __shared__ __align__(16) char lds[41216];
    char* cbA = lds;
    char* cbB = lds + 16384;
    float* bias_s = (float*)(lds + 34816);

    const int tid  = threadIdx.x;
    const int wid  = tid >> 6;          // 0..3
    const int wtid = tid & 63;
    const int l31  = wtid & 31;
    const int half = wtid >> 5;
    const int e0   = blockIdx.x * 128 + wid * 32;
    const bool active = (e0 < NEDGE);   // NEDGE % 32 == 0: whole waves

    char*  h_s = cbB + wid * 4096;      // [32 edges][64 hid] bf16, swizzled; dead before phase-1 DMA
    float* shb = (float*)(lds + 32768 + wid * 512);
    const int swzl = (l31 & 7) << 4;

#define STAGE1(CH, BUF, J) do { \
        const int _o = (wid * 4 + (J)) * 1024 + wtid * 16; \
        stage16((const char*)fc2_wt + (CH) * 16384 + _o, (BUF) + (wid * 4 + (J)) * 1024); \
    } while (0)
#define STAGE_FULL(CH, BUF) do { STAGE1(CH,BUF,0); STAGE1(CH,BUF,1); STAGE1(CH,BUF,2); STAGE1(CH,BUF,3); } while (0)

    STAGE_FULL(0, cbA);   // chunk 0 in flight; overlaps prologue (cbA untouched below)

    // ---- bias -> LDS (400 f32x4) ----
    *(f32x4*)(bias_s + tid * 4) = *(const f32x4*)(fc2_b + tid * 4);
    if (tid < 144)
        *(f32x4*)(bias_s + (tid + 256) * 4) = *(const f32x4*)(fc2_b + (tid + 256) * 4);

    // ---- edge meta: lanes 0..31 own one edge ----
    int dst_r = 0;
    if (active && wtid < 32) {
        dst_r = edge_index[NEDGE + e0 + wtid];
        atomicAdd(&hist[edge_index[e0 + wtid]], 1);
        *(f32x4*)(shb + wtid * 4) = *(const f32x4*)(edge_sh + (size_t)(e0 + wtid) * 4);
    }

    bf16x8 hb[4];
    f32x4 shv = {0.f, 0.f, 0.f, 0.f};
    float cb1r[16], c10r[12], c11r[4];
    int vs[2];
    vs[0] = l31 * 4;
    vs[1] = (32 + l31) * 4;

    if (active) {
        const int dstm = __shfl(dst_r, l31, 64);
        const float* nap = node_attr + (size_t)dstm * 56;
        shv = *(const f32x4*)(shb + l31 * 4);   // same-wave LDS RAW, in-order

        const f32x4 t0 = *(const f32x4*)(nap + half * 16);
        const f32x4 t1 = *(const f32x4*)(nap + half * 16 + 4);
        const f32x4 t2 = *(const f32x4*)(nap + half * 16 + 8);
        const f32x4 t3 = *(const f32x4*)(nap + half * 16 + 12);
        #pragma unroll
        for (int j = 0; j < 4; j++) {
            cb1r[j]      = INV40f * t0[j];
            cb1r[4 + j]  = INV40f * t1[j];
            cb1r[8 + j]  = INV40f * t2[j];
            cb1r[12 + j] = INV40f * t3[j];
        }
        const f32x4 y0 = *(const f32x4*)(nap + 32 + half * 12);
        const f32x4 y1 = *(const f32x4*)(nap + 32 + half * 12 + 4);
        const f32x4 y2 = *(const f32x4*)(nap + 32 + half * 12 + 8);
        float xx[12];
        #pragma unroll
        for (int j = 0; j < 4; j++) { xx[j] = y0[j]; xx[4 + j] = y1[j]; xx[8 + j] = y2[j]; }
        const float i40s0 = INV40f * shv[0];
        #pragma unroll
        for (int k = 0; k < 12; k++) c10r[k] = i40s0 * xx[k];
        #pragma unroll
        for (int e = 0; e < 4; e++)
            c11r[e] = INV120f * (xx[e*3]*shv[1] + xx[e*3+1]*shv[2] + xx[e*3+2]*shv[3]);

        // ---- fc1: h = relu(ea @ fc1_w + b) with 32x32x16 MFMA ----
        const float* pe = edge_attr + (size_t)(e0 + l31) * 64 + half * 8;
        bf16x8 eb[4];
        #pragma unroll
        for (int s = 0; s < 4; s++) {
            const f32x4 a = *(const f32x4*)(pe + s * 16);
            const f32x4 b = *(const f32x4*)(pe + s * 16 + 4);
            #pragma unroll
            for (int i = 0; i < 4; i++) { eb[s][i] = f2bf(a[i]); eb[s][4 + i] = f2bf(b[i]); }
        }
        #pragma unroll
        for (int g = 0; g < 2; g++) {
            f32x16 c;
            #pragma unroll
            for (int q = 0; q < 4; q++) {
                const f32x4 bq = *(const f32x4*)(fc1_b + g*32 + q*8 + half*4);
                c[q*4+0] = bq[0]; c[q*4+1] = bq[1]; c[q*4+2] = bq[2]; c[q*4+3] = bq[3];
            }
            #pragma unroll
            for (int s = 0; s < 4; s++) {
                const bf16x8 af = *(const bf16x8*)(fc1_wt + (g*32 + l31)*64 + s*16 + half*8);
                c = MFMA32(af, eb[s], c);
            }
            #pragma unroll
            for (int q = 0; q < 4; q++) {
                short4v p;
                #pragma unroll
                for (int j = 0; j < 4; j++) p[j] = f2bf(fmaxf(c[q*4+j], 0.0f));
                *(short4v*)(h_s + (l31*128 + ((g*64 + q*16 + half*8) ^ swzl))) = p;
            }
        }
        // read back B-frags: h[edge=l31][k = s*16 + half*8 + 0..7]
        #pragma unroll
        for (int s = 0; s < 4; s++)
            hb[s] = *(const bf16x8*)(h_s + (l31*128 + ((s*32 + half*16) ^ swzl)));
    }

    // ---- fc2 + TP consume ----
    float acc0[16] = {};
    float ab1[4] = {0,0,0,0};
    float b2[12] = {};

    // fragment-major LDS: weight frag (group go, col l31, slot t=s*2+half) at go*4096 + t*512 + l31*16
    auto mload = [&](const char* cb, int go, int G) -> f32x16 {
        f32x16 c;
        #pragma unroll
        for (int q = 0; q < 4; q++) {
            const f32x4 bq = *(const f32x4*)(bias_s + G*32 + q*8 + half*4);
            c[q*4+0] = bq[0]; c[q*4+1] = bq[1]; c[q*4+2] = bq[2]; c[q*4+3] = bq[3];
        }
        #pragma unroll
        for (int s = 0; s < 4; s++) {
            const bf16x8 a = *(const bf16x8*)(cb + go*4096 + (s*2 + half)*512 + l31*16);
            c = MFMA32(a, hb[s], c);
        }
        return c;
    };

    auto cons_w00 = [&](const char* cb, int ch) {
        #pragma unroll
        for (int go = 0; go < 4; go++) {
            const int G = ch * 4 + go;                  // u = G
            const f32x16 c = mload(cb, go, G);
            const float cv = shv[0] * bperm(vs[G >> 4], cb1r[G & 15]);
            #pragma unroll
            for (int r = 0; r < 16; r++) acc0[r] += cv * c[r];
        }
    };
    auto cons_w01 = [&](const char* cb, int Gl0) {
        #pragma unroll
        for (int go = 0; go < 4; go++) {
            const int Gl = Gl0 + go;                    // 0..7
            const f32x16 c = mload(cb, go, 32 + Gl);
            #pragma unroll
            for (int q = 0; q < 4; q++) {
                const int u = Gl * 4 + q;               // 0..31
                const float cvq = bperm(vs[u >> 4], cb1r[u & 15]);
                #pragma unroll
                for (int j = 0; j < 4; j++) ab1[j] += cvq * c[q*4+j];
            }
        }
    };
    auto cons_w10 = [&](const char* cb) {
        #pragma unroll
        for (int go = 0; go < 2; go++) {
            const f32x16 c = mload(cb, go, 40 + go);
            #pragma unroll
            for (int q = 0; q < 4; q++) {
                const int u = go * 4 + q;               // 0..7
                #pragma unroll
                for (int i = 0; i < 3; i++) {
                    const float cv = bperm(vs[u >> 2], c10r[(u & 3) * 3 + i]);
                    #pragma unroll
                    for (int j = 0; j < 4; j++) b2[j*3+i] += cv * c[q*4+j];
                }
            }
        }
    };
    auto cons_w11_2 = [&](const char* cb, int goBase, int Gl0) {
        #pragma unroll
        for (int go = 0; go < 2; go++) {
            const int Gl = Gl0 + go;                    // u = Gl (0..7)
            const f32x16 c = mload(cb, goBase + go, 42 + Gl);
            const float cv = bperm(vs[Gl >> 2], c11r[Gl & 3]);
            #pragma unroll
            for (int r = 0; r < 16; r++) acc0[r] += cv * c[r];
        }
    };
    auto cons_w11_4 = [&](const char* cb, int Gl0) {
        #pragma unroll
        for (int go = 0; go < 4; go++) {
            const int Gl = Gl0 + go;
            const f32x16 c = mload(cb, go, 42 + Gl);
            const float cv = bperm(vs[Gl >> 2], c11r[Gl & 3]);
            #pragma unroll
            for (int r = 0; r < 16; r++) acc0[r] += cv * c[r];
        }
    };

    // ---- 13-phase chunk pipeline (R12 schedule, 1 barrier/phase) ----
    __syncthreads();                                   // chunk 0 + bias ready; h reads done
    STAGE_FULL(1,  cbB); if (active) cons_w00(cbA, 0); __syncthreads();
    STAGE_FULL(2,  cbA); if (active) cons_w00(cbB, 1); __syncthreads();
    STAGE_FULL(3,  cbB); if (active) cons_w00(cbA, 2); __syncthreads();
    STAGE_FULL(4,  cbA); if (active) cons_w00(cbB, 3); __syncthreads();
    STAGE_FULL(5,  cbB); if (active) cons_w00(cbA, 4); __syncthreads();
    STAGE_FULL(6,  cbA); if (active) cons_w00(cbB, 5); __syncthreads();
    STAGE_FULL(7,  cbB); if (active) cons_w00(cbA, 6); __syncthreads();
    STAGE_FULL(8,  cbA); if (active) cons_w00(cbB, 7); __syncthreads();
    STAGE_FULL(9,  cbB); if (active) cons_w01(cbA, 0); __syncthreads();
    STAGE_FULL(10, cbA); if (active) cons_w01(cbB, 4); __syncthreads();
    STAGE_FULL(11, cbB); if (active) { cons_w10(cbA); cons_w11_2(cbA, 2, 0); } __syncthreads();
    STAGE_FULL(12, cbA); if (active) cons_w11_4(cbB, 2); __syncthreads();
                         if (active) cons_w11_2(cbA, 0, 6);

    if (!active) return;

    // ---- emit: each lane owns full (edge=l31, w-subset) results; no reductions ----
    float* orow = tp_out + (size_t)(e0 + l31) * 56;
    #pragma unroll
    for (int q = 0; q < 4; q++)
        *(f32x4*)(orow + q*8 + half*4) = f32x4{acc0[q*4], acc0[q*4+1], acc0[q*4+2], acc0[q*4+3]};
    float ov[12];
    #pragma unroll
    for (int j = 0; j < 4; j++) {
        ov[j*3 + 0] = shv[1] * ab1[j] + b2[j*3 + 0];
        ov[j*3 + 1] = shv[2] * ab1[j] + b2[j*3 + 1];
        ov[j*3 + 2] = shv[3] * ab1[j] + b2[j*3 + 2];
    }
    float* p1 = orow + 32 + half * 12;
    *(f32x4*)(p1)     = f32x4{ov[0], ov[1], ov[2],  ov[3]};
    *(f32x4*)(p1 + 4) = f32x4{ov[4], ov[5], ov[6],  ov[7]};
    *(f32x4*)(p1 + 8) = f32x4{ov[8], ov[9], ov[10], ov[11]};
#undef STAGE1
#undef STAGE_FULL
}

// exclusive prefix scan of hist[10000] -> offsets[10001], cursor (1024 threads, 10/thread)
__global__ __launch_bounds__(1024) void scan_hist(const int* __restrict__ hist,
                                                  int* __restrict__ offsets,
                                                  int* __restrict__ cursor) {
    __shared__ int part[1024];
    const int t = threadIdx.x;
    const int n0 = t * 10;
    int lh[10];
    int s = 0;
    if (n0 < NNODE) {
        #pragma unroll
        for (int j = 0; j < 10; j++) { lh[j] = hist[n0 + j]; s += lh[j]; }
    }
    part[t] = s;
    __syncthreads();
    for (int d = 1; d < 1024; d <<= 1) {
        const int v = (t >= d) ? part[t - d] : 0;
        __syncthreads();
        part[t] += v;
        __syncthreads();
    }
    if (n0 < NNODE) {
        int run = part[t] - s;
        #pragma unroll
        for (int j = 0; j < 10; j++) {
            offsets[n0 + j] = run; cursor[n0 + j] = run; run += lh[j];
        }
    }
    if (t == 0) offsets[NNODE] = NEDGE;
}

__global__ __launch_bounds__(256) void fill_perm(const int* __restrict__ edge_index,
                                                 int* __restrict__ cursor,
                                                 int* __restrict__ perm) {
    const int e = blockIdx.x * 256 + threadIdx.x;
    if (e < NEDGE) {
        const int s = edge_index[e];
        const int p = atomicAdd(&cursor[s], 1);
        perm[p] = e;
    }
}

// gather-based segment mean + residual + BN partial stats
__global__ __launch_bounds__(256) void node_agg(
    const float* __restrict__ tp_out, const int* __restrict__ offsets,
    const int* __restrict__ perm,
    const float* __restrict__ node_attr, float* __restrict__ out,
    float* __restrict__ stats)
{
    __shared__ float part[72];
    const int tid = threadIdx.x;
    if (tid < 72) part[tid] = 0.0f;
    __syncthreads();
    const int n = blockIdx.x * 16 + (tid >> 4);
    const int q = tid & 15;
    if (n < NNODE && q < 14) {
        const int st = offsets[n], en = offsets[n + 1];
        f32x4 acc = {0.f, 0.f, 0.f, 0.f};
        for (int r = st; r < en; r++)
            acc += *(const f32x4*)(tp_out + (size_t)perm[r] * 56 + q * 4);
        const float inv = 1.0f / fmaxf((float)(en - st), 1.0f);
        const int c0 = q * 4;
        const f32x4 res = *(const f32x4*)(node_attr + (size_t)n * 56 + c0);
        f32x4 val;
        #pragma unroll
        for (int j = 0; j < 4; j++) {
            val[j] = acc[j] * inv + res[j];
            const int c = c0 + j;
            if (c < 32) {
                atomicAdd(&part[c], val[j]);
                atomicAdd(&part[32 + c], val[j] * val[j]);
            } else {
                atomicAdd(&part[64 + (c - 32) / 3], val[j] * val[j]);
            }
        }
        *(f32x4*)(out + (size_t)n * 56 + c0) = val;
    }
    __syncthreads();
    if (tid < 72) unsafeAtomicAdd(&stats[tid], part[tid]);
}

__global__ __launch_bounds__(256) void node_norm(
    float* __restrict__ out, const float* __restrict__ stats,
    const float* __restrict__ g0, const float* __restrict__ b0,
    const float* __restrict__ g1)
{
    const int id = blockIdx.x * 256 + threadIdx.x;
    if (id >= NNODE * 56) return;
    const int c = id % 56;
    float val = out[id];
    if (c < 32) {
        const float m   = stats[c]      * (1.0f / NNODE);
        const float ex2 = stats[32 + c] * (1.0f / NNODE);
        const float var = ex2 - m * m;
        val = (val - m) * rsqrtf(var + 1e-5f) * g0[c] + b0[c];
    } else {
        const int v = (c - 32) / 3;
        const float vn = stats[64 + v] * (1.0f / (3.0f * NNODE));
        val = val * rsqrtf(vn + 1e-5f) * g1[v];
    }
    out[id] = val;
}

extern "C" void kernel_launch(void* const* d_in, const int* in_sizes, int n_in,
                              void* d_out, int out_size, void* d_ws, size_t ws_size,
                              hipStream_t stream) {
    const float* node_attr = (const float*)d_in[0];
    const float* edge_attr = (const float*)d_in[1];
    const float* edge_sh   = (const float*)d_in[2];
    const int*   edge_index= (const int*)  d_in[3];
    const float* fc1_w     = (const float*)d_in[4];
    const float* fc1_b     = (const float*)d_in[5];
    const float* fc2_w     = (const float*)d_in[6];
    const float* fc2_b     = (const float*)d_in[7];
    const float* g0        = (const float*)d_in[8];
    const float* b0        = (const float*)d_in[9];
    const float* g1        = (const float*)d_in[10];
    float* out = (float*)d_out;

    char* ws = (char*)d_ws;
    float* stats   = (float*)(ws + 0);
    int*   hist    = (int*)  (ws + 288);
    int*   offsets = (int*)  (ws + 40288);
    int*   cursor  = (int*)  (ws + 80320);
    int*   perm    = (int*)  (ws + 120320);
    short* fc1_wt  = (short*)(ws + 520320);
    short* fc2_wt  = (short*)(ws + 528512);
    float* tp_out  = (float*)(ws + 733312);

    prep<<<67, 256, 0, stream>>>(fc1_w, fc2_w, fc1_wt, fc2_wt, stats, hist);
    edge_fused<<<782, 256, 0, stream>>>(node_attr, edge_attr, edge_sh, edge_index,
                                        fc1_b, fc2_b, fc1_wt, fc2_wt, tp_out, hist);
    scan_hist<<<1, 1024, 0, stream>>>(hist, offsets, cursor);
    fill_perm<<<391, 256, 0, stream>>>(edge_index, cursor, perm);
    node_agg<<<625, 256, 0, stream>>>(tp_out, offsets, perm, node_attr, out, stats);
    node_norm<<<2188, 256, 0, stream>>>(out, stats, g0, b0, g1);
}